// Round 11
// baseline (42.338 us; speedup 1.0000x reference)
//
#include <hip/hip_runtime.h>
#include <cmath>

#define S_SUB 512
#define T_TR  8192
#define D_IN  8
#define BLK   1024         // one block per subject
#define CH    (T_TR/BLK)   // 8 trials per thread
#define NW    (BLK/64)     // 16 waves per block

typedef float f4 __attribute__((ext_vector_type(4)));

// ---------------------------------------------------------------------------
// Single kernel, one block per SUBJECT (validated r10 structure).
//  - NEW vs r10: registers prefetch the first TWO phase-B input groups
//    (j=0,1 -> 16 VGPR) and all 8 u_bern scalars before phase A, so the
//    phase-B HBM stream starts concurrently with the eps_x read + scan
//    instead of idling behind the barrier.
//  - phase B keeps the r7/r10 scalar mapping t = j*BLK + tid (lane-stride
//    32 B; r8/r9's 128 B lane-stride remap regressed).
//  - tid==0 computes the f64 param chain (erfcinv + 2 Newton steps,
//    bit-identical to the validated setup_kernel), LDS broadcast.
// LDS 73.9 KiB -> 2 blocks/CU x 16 waves = 32 waves/CU.
// ---------------------------------------------------------------------------
__global__ __launch_bounds__(BLK, 8) void mono_kernel(
    const float* __restrict__ inputs,
    const float* __restrict__ eps_w,
    const float* __restrict__ u_a,
    const float* __restrict__ sigmasq,
    const float* __restrict__ eps_mu,
    const float* __restrict__ eps_x0,
    const float* __restrict__ eps_x,
    const float* __restrict__ u_bern,
    double Fa, double dF,
    float* __restrict__ out_x,
    float* __restrict__ out_y)
{
    const int s    = blockIdx.x;
    const int tid  = threadIdx.x;
    const int lane = tid & 63;
    const int wid  = tid >> 6;

    __shared__ double2 wtot[NW];
    __shared__ double  pl[4];                // a, b, sd, x0 broadcast
    __shared__ double  xs[BLK * (CH + 1)];   // pad-9 transpose buffer (73.7 KiB)

    const size_t subjbase = (size_t)s * T_TR;
    const size_t base     = subjbase + (size_t)tid * CH;

    // ---- issue this thread's eps_x loads first ----
    const f4* e4 = (const f4*)(eps_x + base);
    f4 o0 = e4[0];
    f4 o1 = e4[1];

    // ---- prefetch phase-B head: inputs groups j=0,1 + all u_bern ----
    const f4* in4 = (const f4*)(inputs + subjbase * D_IN);
    f4 pi00 = in4[2*tid];               // j=0, t = tid
    f4 pi01 = in4[2*tid + 1];
    f4 pi10 = in4[2*(BLK + tid)];       // j=1, t = BLK + tid
    f4 pi11 = in4[2*(BLK + tid) + 1];
    float uv[CH];
    #pragma unroll
    for (int j = 0; j < CH; ++j)
        uv[j] = u_bern[subjbase + j * BLK + tid];

    // ---- per-subject parameter chain, one lane per block (f64, identical
    //      math to the validated setup_kernel) ----
    if (tid == 0) {
        const double RS2 = 0.7071067811865476;     // 1/sqrt(2)
        const double S2  = 1.4142135623730951;     // sqrt(2)
        const double ISQ = 0.3989422804014327;     // 1/sqrt(2*pi)
        double p = fma((double)u_a[s], dF, Fa);
        double z = -S2 * erfcinv(2.0 * p);
        #pragma unroll
        for (int it = 0; it < 2; ++it) {           // Newton polish: Phi(z)=p
            double F   = 0.5 * erfc(-z * RS2);
            double pdf = exp(-0.5 * z * z) * ISQ;
            z -= (F - p) / pdf;
        }
        double a  = 0.99 + 0.1 * z;
        double mu = (double)eps_mu[s];
        pl[0] = a;
        pl[1] = mu * (1.0 - a);                    // b
        pl[2] = sqrt((double)sigmasq[s]);          // sd
        pl[3] = mu + (double)eps_x0[s];            // x0
    }
    __syncthreads();
    const double a  = pl[0];
    const double b  = pl[1];
    const double sd = pl[2];
    const double x0 = pl[3];

    float ev[CH];
    ev[0]=o0.x; ev[1]=o0.y; ev[2]=o0.z; ev[3]=o0.w;
    ev[4]=o1.x; ev[5]=o1.y; ev[6]=o1.z; ev[7]=o1.w;

    // ---- phase 1: local affine compose over the chunk ----
    double A = 1.0, Bv = 0.0;
    #pragma unroll
    for (int j = 0; j < CH; ++j) {
        double c = fma(sd, (double)ev[j], b);
        Bv = fma(a, Bv, c);
        A *= a;
    }

    // ---- phase 2a: inclusive wave scan (shfl_up Hillis-Steele) ----
    #pragma unroll
    for (int off = 1; off < 64; off <<= 1) {
        double pA = __shfl_up(A, off);
        double pB = __shfl_up(Bv, off);
        if (lane >= off) {
            Bv = fma(A, pB, Bv);              // cur ∘ prev
            A  = A * pA;
        }
    }
    if (lane == 63) wtot[wid] = make_double2(A, Bv);
    __syncthreads();

    // ---- phase 2b: exclusive cross-wave prefix (16 waves) ----
    double PA = 1.0, PB = 0.0;
    for (int w = 0; w < wid; ++w) {
        double2 t = wtot[w];
        PB = fma(t.x, PB, t.y);
        PA = t.x * PA;
    }
    double eA = __shfl_up(A, 1);
    double eB = __shfl_up(Bv, 1);
    if (lane == 0) { eA = 1.0; eB = 0.0; }
    double EB = fma(eA, PB, eB);
    double EA = eA * PA;
    double x  = fma(EA, x0, EB);              // x at start of this chunk

    // ---- phase A replay: deposit x_t (f64, pre-update) into LDS ----
    #pragma unroll
    for (int j = 0; j < CH; ++j) {
        xs[tid * (CH + 1) + j] = x;
        double c = fma(sd, (double)ev[j], b);
        x = fma(a, x, c);
    }
    __syncthreads();

    // ---- phase B: r7 scalar mapping, trial = j*BLK + tid ----
    const float* wp = eps_w + s * D_IN;
    const double w0 = (double)wp[0], w1 = (double)wp[1];
    const double w2 = (double)wp[2], w3 = (double)wp[3];
    const double w4 = (double)wp[4], w5 = (double)wp[5];
    const double w6 = (double)wp[6], w7 = (double)wp[7];

    #pragma unroll
    for (int j = 0; j < CH; ++j) {
        const int t = j * BLK + tid;
        f4 i0, i1;
        if (j == 0)      { i0 = pi00; i1 = pi01; }
        else if (j == 1) { i0 = pi10; i1 = pi11; }
        else             { i0 = in4[2*t]; i1 = in4[2*t + 1]; }
        double xv = xs[(t >> 3) * (CH + 1) + (t & 7)];
        double dot = fma((double)i0.x, w0,
                     fma((double)i0.y, w1,
                     fma((double)i0.z, w2,
                     fma((double)i0.w, w3,
                     fma((double)i1.x, w4,
                     fma((double)i1.y, w5,
                     fma((double)i1.z, w6, (double)i1.w * w7)))))));
        double L = xv + dot;
        double E = exp(-L);
        out_y[subjbase + t] = ((double)uv[j] * (1.0 + E) < 1.0) ? 1.0f : 0.0f;
        out_x[subjbase + t] = (float)xv;
    }
}

extern "C" void kernel_launch(void* const* d_in, const int* in_sizes, int n_in,
                              void* d_out, int out_size, void* d_ws, size_t ws_size,
                              hipStream_t stream) {
    const float* inputs  = (const float*)d_in[0];   // [S,T,D]
    const float* eps_w   = (const float*)d_in[1];   // [S,D]
    const float* u_a     = (const float*)d_in[2];   // [S]
    const float* sigmasq = (const float*)d_in[3];   // [S]
    const float* eps_mu  = (const float*)d_in[4];   // [S]
    const float* eps_x0  = (const float*)d_in[5];   // [S]
    const float* eps_x   = (const float*)d_in[6];   // [S,T]
    const float* u_bern  = (const float*)d_in[7];   // [S,T]

    float* out = (float*)d_out;                     // [x | y] f32

    // input-independent truncation constants (host f64 libm)
    const double RS2 = 0.7071067811865476;
    const double Fa  = 0.5 * erfc(9.9 * RS2);       // Phi(-9.9)
    const double Fb  = 0.5 * erfc(-0.1 * RS2);      // Phi(0.1)
    const double dF  = Fb - Fa;

    mono_kernel<<<S_SUB, BLK, 0, stream>>>(inputs, eps_w, u_a, sigmasq, eps_mu,
                                           eps_x0, eps_x, u_bern, Fa, dF,
                                           out, out + (size_t)S_SUB * T_TR);
}

// Round 12
// 36.341 us; speedup vs baseline: 1.1650x; 1.1650x over previous
//
#include <hip/hip_runtime.h>
#include <cmath>

#define S_SUB 512
#define T_TR  8192
#define D_IN  8
#define BLK   1024         // one block per subject
#define CH    (T_TR/BLK)   // 8 trials per thread
#define NW    (BLK/64)     // 16 waves per block

typedef float f4 __attribute__((ext_vector_type(4)));

// ---------------------------------------------------------------------------
// Single kernel, one block per SUBJECT (validated r10 structure).
//  - vs r10, ONE change: the 8 scalar u_bern loads (8 VGPRs) are hoisted
//    above the param chain + scan, so 16 MB of the phase-B stream overlaps
//    the scan-idle window. r11's heavier prefetch (24 B/thread) spilled to
//    scratch (+28 MB WRITE_SIZE) under the 64-VGPR cap and regressed; this
//    version stays ~40-48 VGPR.
//  - phase B keeps the r7/r10 scalar mapping t = j*BLK + tid (lane-stride
//    32 B on inputs; r8/r9's 128 B lane-stride remap regressed).
//  - tid==0 computes the f64 param chain (erfcinv + 2 Newton steps,
//    bit-identical to the validated setup_kernel), LDS broadcast.
// LDS 73.9 KiB -> 2 blocks/CU x 16 waves = 32 waves/CU.
// ---------------------------------------------------------------------------
__global__ __launch_bounds__(BLK, 8) void mono_kernel(
    const float* __restrict__ inputs,
    const float* __restrict__ eps_w,
    const float* __restrict__ u_a,
    const float* __restrict__ sigmasq,
    const float* __restrict__ eps_mu,
    const float* __restrict__ eps_x0,
    const float* __restrict__ eps_x,
    const float* __restrict__ u_bern,
    double Fa, double dF,
    float* __restrict__ out_x,
    float* __restrict__ out_y)
{
    const int s    = blockIdx.x;
    const int tid  = threadIdx.x;
    const int lane = tid & 63;
    const int wid  = tid >> 6;

    __shared__ double2 wtot[NW];
    __shared__ double  pl[4];                // a, b, sd, x0 broadcast
    __shared__ double  xs[BLK * (CH + 1)];   // pad-9 transpose buffer (73.7 KiB)

    const size_t subjbase = (size_t)s * T_TR;
    const size_t base     = subjbase + (size_t)tid * CH;

    // ---- issue this thread's eps_x loads first ----
    const f4* e4 = (const f4*)(eps_x + base);
    f4 o0 = e4[0];
    f4 o1 = e4[1];

    // ---- light prefetch: the 8 u_bern scalars (phase-B mapping, 8 VGPRs) ----
    float uv[CH];
    #pragma unroll
    for (int j = 0; j < CH; ++j)
        uv[j] = u_bern[subjbase + j * BLK + tid];

    // ---- per-subject parameter chain, one lane per block (f64, identical
    //      math to the validated setup_kernel) ----
    if (tid == 0) {
        const double RS2 = 0.7071067811865476;     // 1/sqrt(2)
        const double S2  = 1.4142135623730951;     // sqrt(2)
        const double ISQ = 0.3989422804014327;     // 1/sqrt(2*pi)
        double p = fma((double)u_a[s], dF, Fa);
        double z = -S2 * erfcinv(2.0 * p);
        #pragma unroll
        for (int it = 0; it < 2; ++it) {           // Newton polish: Phi(z)=p
            double F   = 0.5 * erfc(-z * RS2);
            double pdf = exp(-0.5 * z * z) * ISQ;
            z -= (F - p) / pdf;
        }
        double a  = 0.99 + 0.1 * z;
        double mu = (double)eps_mu[s];
        pl[0] = a;
        pl[1] = mu * (1.0 - a);                    // b
        pl[2] = sqrt((double)sigmasq[s]);          // sd
        pl[3] = mu + (double)eps_x0[s];            // x0
    }
    __syncthreads();
    const double a  = pl[0];
    const double b  = pl[1];
    const double sd = pl[2];
    const double x0 = pl[3];

    float ev[CH];
    ev[0]=o0.x; ev[1]=o0.y; ev[2]=o0.z; ev[3]=o0.w;
    ev[4]=o1.x; ev[5]=o1.y; ev[6]=o1.z; ev[7]=o1.w;

    // ---- phase 1: local affine compose over the chunk ----
    double A = 1.0, Bv = 0.0;
    #pragma unroll
    for (int j = 0; j < CH; ++j) {
        double c = fma(sd, (double)ev[j], b);
        Bv = fma(a, Bv, c);
        A *= a;
    }

    // ---- phase 2a: inclusive wave scan (shfl_up Hillis-Steele) ----
    #pragma unroll
    for (int off = 1; off < 64; off <<= 1) {
        double pA = __shfl_up(A, off);
        double pB = __shfl_up(Bv, off);
        if (lane >= off) {
            Bv = fma(A, pB, Bv);              // cur ∘ prev
            A  = A * pA;
        }
    }
    if (lane == 63) wtot[wid] = make_double2(A, Bv);
    __syncthreads();

    // ---- phase 2b: exclusive cross-wave prefix (16 waves) ----
    double PA = 1.0, PB = 0.0;
    for (int w = 0; w < wid; ++w) {
        double2 t = wtot[w];
        PB = fma(t.x, PB, t.y);
        PA = t.x * PA;
    }
    double eA = __shfl_up(A, 1);
    double eB = __shfl_up(Bv, 1);
    if (lane == 0) { eA = 1.0; eB = 0.0; }
    double EB = fma(eA, PB, eB);
    double EA = eA * PA;
    double x  = fma(EA, x0, EB);              // x at start of this chunk

    // ---- phase A replay: deposit x_t (f64, pre-update) into LDS ----
    #pragma unroll
    for (int j = 0; j < CH; ++j) {
        xs[tid * (CH + 1) + j] = x;
        double c = fma(sd, (double)ev[j], b);
        x = fma(a, x, c);
    }
    __syncthreads();

    // ---- phase B: r7 scalar mapping, trial = j*BLK + tid ----
    const float* wp = eps_w + s * D_IN;
    const double w0 = (double)wp[0], w1 = (double)wp[1];
    const double w2 = (double)wp[2], w3 = (double)wp[3];
    const double w4 = (double)wp[4], w5 = (double)wp[5];
    const double w6 = (double)wp[6], w7 = (double)wp[7];

    const f4* in4 = (const f4*)(inputs + subjbase * D_IN);
    #pragma unroll
    for (int j = 0; j < CH; ++j) {
        const int t = j * BLK + tid;
        f4 i0 = in4[2*t];
        f4 i1 = in4[2*t + 1];
        double xv = xs[(t >> 3) * (CH + 1) + (t & 7)];
        double dot = fma((double)i0.x, w0,
                     fma((double)i0.y, w1,
                     fma((double)i0.z, w2,
                     fma((double)i0.w, w3,
                     fma((double)i1.x, w4,
                     fma((double)i1.y, w5,
                     fma((double)i1.z, w6, (double)i1.w * w7)))))));
        double L = xv + dot;
        double E = exp(-L);
        out_y[subjbase + t] = ((double)uv[j] * (1.0 + E) < 1.0) ? 1.0f : 0.0f;
        out_x[subjbase + t] = (float)xv;
    }
}

extern "C" void kernel_launch(void* const* d_in, const int* in_sizes, int n_in,
                              void* d_out, int out_size, void* d_ws, size_t ws_size,
                              hipStream_t stream) {
    const float* inputs  = (const float*)d_in[0];   // [S,T,D]
    const float* eps_w   = (const float*)d_in[1];   // [S,D]
    const float* u_a     = (const float*)d_in[2];   // [S]
    const float* sigmasq = (const float*)d_in[3];   // [S]
    const float* eps_mu  = (const float*)d_in[4];   // [S]
    const float* eps_x0  = (const float*)d_in[5];   // [S]
    const float* eps_x   = (const float*)d_in[6];   // [S,T]
    const float* u_bern  = (const float*)d_in[7];   // [S,T]

    float* out = (float*)d_out;                     // [x | y] f32

    // input-independent truncation constants (host f64 libm)
    const double RS2 = 0.7071067811865476;
    const double Fa  = 0.5 * erfc(9.9 * RS2);       // Phi(-9.9)
    const double Fb  = 0.5 * erfc(-0.1 * RS2);      // Phi(0.1)
    const double dF  = Fb - Fa;

    mono_kernel<<<S_SUB, BLK, 0, stream>>>(inputs, eps_w, u_a, sigmasq, eps_mu,
                                           eps_x0, eps_x, u_bern, Fa, dF,
                                           out, out + (size_t)S_SUB * T_TR);
}